// Round 2
// baseline (221.831 us; speedup 1.0000x reference)
//
#include <hip/hip_runtime.h>

typedef unsigned short u16;
typedef unsigned int u32;

typedef __bf16 bf16x8 __attribute__((ext_vector_type(8)));
typedef float f32x4 __attribute__((ext_vector_type(4)));

union V16 { uint4 u; bf16x8 v; u16 s[8]; };
union F4  { float4 v; float f[4]; };

__device__ __forceinline__ u16 f2bf(float f) {
  union { float f; u32 u; } c; c.f = f;
  u32 u = c.u;
  u += 0x7fffu + ((u >> 16) & 1u);   // RNE
  return (u16)(u >> 16);
}

#define Z_OFF   131072
#define ZM_OFF  147456
#define ZLV_OFF 163840

// ---------------------------------------------------------------------------
// Pack gen1_w / gen2_w (fp32) into bf16 MFMA B-fragment order (16x16x32):
// b_frag element j of lane: B[k = s*32 + (lane>>4)*8 + j][n = t*16 + (lane&15)]
// B1[k=l][n=h] = gen1_w[h][l]  (N padded 300->320, zeros)
// B2[k=h][n=g] = gen2_w[g][h]  (K and N padded 300->320, zeros)
// ws layout (u16): [0 .. 20479] = b1pack (20 t * 2 s * 64 lanes * 8)
//                  [20480 .. 122879] = b2pack (20 t * 10 s * 64 lanes * 8)
// ---------------------------------------------------------------------------
__global__ __launch_bounds__(256) void pack_kernel(const float* __restrict__ g1w,
                                                   const float* __restrict__ g2w,
                                                   u16* __restrict__ ws) {
  const int n = blockIdx.x * 256 + threadIdx.x;
  if (n < 2560) {
    const int lane = n & 63;
    const int rest = n >> 6;
    const int s = rest & 1;
    const int t = rest >> 1;
    const int ncol = t * 16 + (lane & 15);
    const int k0 = s * 32 + (lane >> 4) * 8;
    V16 v;
#pragma unroll
    for (int j = 0; j < 8; ++j)
      v.s[j] = (ncol < 300) ? f2bf(g1w[ncol * 64 + k0 + j]) : (u16)0;
    *(uint4*)(ws + n * 8) = v.u;
  } else if (n < 15360) {
    const int m = n - 2560;
    const int lane = m & 63;
    const int rest = m >> 6;
    const int s = rest % 10;
    const int t = rest / 10;
    const int g = t * 16 + (lane & 15);
    const int k0 = s * 32 + (lane >> 4) * 8;
    V16 v;
#pragma unroll
    for (int j = 0; j < 8; ++j) {
      const int h = k0 + j;
      v.s[j] = (g < 300 && h < 300) ? f2bf(g2w[g * 300 + h]) : (u16)0;
    }
    *(uint4*)(ws + 20480 + m * 8) = v.u;
  }
}

// ---------------------------------------------------------------------------
// Encoder: one block per batch row b. Full fp32 (protects z/z_mean/z_log_var
// accuracy). Writes z, z_mean, z_log_var into d_out.
// ---------------------------------------------------------------------------
__global__ __launch_bounds__(320) void enc_kernel(
    const float* __restrict__ x, const float* __restrict__ eps,
    const float* __restrict__ e1w, const float* __restrict__ e1b,
    const float* __restrict__ e2w, const float* __restrict__ e2b,
    const float* __restrict__ zmw, const float* __restrict__ zmb,
    const float* __restrict__ zvw, const float* __restrict__ zvb,
    float* __restrict__ out) {
  __shared__ float xs[512];
  __shared__ float h1[304];
  __shared__ float h2[304];
  __shared__ float zms[64], zlvs[64];
  const int b = blockIdx.x, t = threadIdx.x;
  for (int k = t; k < 512; k += 320) xs[k] = x[b * 512 + k];
  __syncthreads();
  if (t < 300) {
    float acc = e1b[t];
    const float4* wr = (const float4*)(e1w + t * 512);
#pragma unroll 4
    for (int cc = 0; cc < 128; ++cc) {
      F4 u; u.v = wr[cc];
      const float* xp = xs + cc * 4;
      acc += u.f[0] * xp[0] + u.f[1] * xp[1] + u.f[2] * xp[2] + u.f[3] * xp[3];
    }
    h1[t] = fmaxf(acc, 0.f);
  }
  __syncthreads();
  if (t < 300) {
    float acc = e2b[t];
    const float4* wr = (const float4*)(e2w + t * 300);
#pragma unroll 5
    for (int cc = 0; cc < 75; ++cc) {
      F4 u; u.v = wr[cc];
      const float* hp = h1 + cc * 4;
      acc += u.f[0] * hp[0] + u.f[1] * hp[1] + u.f[2] * hp[2] + u.f[3] * hp[3];
    }
    h2[t] = fmaxf(acc, 0.f);
  }
  __syncthreads();
  if (t < 128) {                       // wave 0: z_mean, wave 1: z_log_var
    const int i = t & 63;
    const float* wbase = (t < 64) ? zmw : zvw;
    const float* bbase = (t < 64) ? zmb : zvb;
    float acc = bbase[i];
    const float4* wr = (const float4*)(wbase + i * 300);
#pragma unroll 5
    for (int cc = 0; cc < 75; ++cc) {
      F4 u; u.v = wr[cc];
      const float* hp = h2 + cc * 4;
      acc += u.f[0] * hp[0] + u.f[1] * hp[1] + u.f[2] * hp[2] + u.f[3] * hp[3];
    }
    if (t < 64) zms[i] = acc; else zlvs[i] = acc;
  }
  __syncthreads();
  if (t < 64) {
    const float zm = zms[t], zlv = zlvs[t];
    const float zz = zm + eps[b * 64 + t] * expf(0.5f * zlv);
    out[Z_OFF   + b * 64 + t] = zz;
    out[ZM_OFF  + b * 64 + t] = zm;
    out[ZLV_OFF + b * 64 + t] = zlv;
  }
}

// ---------------------------------------------------------------------------
// Fused decoder. 128 rows (= one b, 128 consecutive d) per WG, 4 waves.
// Stage 2 (GEMM1): each wave computes g1 for its 32 rows -> bf16 LDS tile
//   g1s[128][328] (stride 328: 2-way bank aliasing only, rows 16B-aligned).
// Stage 3 (GEMM2 + head dot): wave grid 2x2 (wr: 64-row half, wc: 10 n-tiles).
//   b-fragments register-held, reused across 4 row-blocks; tile-pairs give
//   8 independent MFMA chains. Epilogue: +gen2_b, relu, *head_w, accumulate;
//   16-lane butterfly + cross-wc LDS reduction, +head_b, store fp32.
// ---------------------------------------------------------------------------
__global__ __launch_bounds__(256) void dec_kernel(
    const float* __restrict__ z,  // [256][64] (fp32, in d_out)
    const float* __restrict__ W,  // [512][64]
    const uint4* __restrict__ b1p,
    const uint4* __restrict__ b2p,
    const float* __restrict__ g2b,  // [300]
    const float* __restrict__ hw,   // [512][300]
    const float* __restrict__ hb,   // [512]
    float* __restrict__ xout)       // [256*512]
{
  __shared__ u16 g1s[128 * 328];
  __shared__ float xred[2][128];

  const int wg = blockIdx.x;
  const int r0 = wg << 7;        // 128 rows per WG; all within one b
  const int bi = r0 >> 9;
  const int d0 = r0 & 511;
  const int tid = threadIdx.x;
  const int w = tid >> 6;
  const int lane = tid & 63;
  const int quad = lane >> 4;
  const int c = lane & 15;

  const float* zrow = z + bi * 64;

  // ---- stage 2: g1 rows 32w .. 32w+31 ----
#pragma unroll
  for (int rbi = 0; rbi < 2; ++rbi) {
    const int rowA = 32 * w + 16 * rbi + c;   // A-operand row for this lane
    const int dA = d0 + rowA;
    const float* Wrow = W + dA * 64;
    bf16x8 af0, af1;
    {
      F4 za, zb, wa, wb; V16 m;
      int l0 = quad * 8;
      za.v = *(const float4*)(zrow + l0);
      zb.v = *(const float4*)(zrow + l0 + 4);
      wa.v = *(const float4*)(Wrow + l0);
      wb.v = *(const float4*)(Wrow + l0 + 4);
#pragma unroll
      for (int j = 0; j < 4; ++j) {
        m.s[j]     = f2bf(za.f[j] * wa.f[j]);
        m.s[4 + j] = f2bf(zb.f[j] * wb.f[j]);
      }
      af0 = m.v;
      l0 = 32 + quad * 8;
      za.v = *(const float4*)(zrow + l0);
      zb.v = *(const float4*)(zrow + l0 + 4);
      wa.v = *(const float4*)(Wrow + l0);
      wb.v = *(const float4*)(Wrow + l0 + 4);
#pragma unroll
      for (int j = 0; j < 4; ++j) {
        m.s[j]     = f2bf(za.f[j] * wa.f[j]);
        m.s[4 + j] = f2bf(zb.f[j] * wb.f[j]);
      }
      af1 = m.v;
    }
    const int rw = 32 * w + 16 * rbi + quad * 4;  // D-operand row base
    for (int t = 0; t < 20; ++t) {
      V16 b0, b1;
      b0.u = b1p[(t * 2 + 0) * 64 + lane];
      b1.u = b1p[(t * 2 + 1) * 64 + lane];
      f32x4 d = {0.f, 0.f, 0.f, 0.f};
      d = __builtin_amdgcn_mfma_f32_16x16x32_bf16(af0, b0.v, d, 0, 0, 0);
      d = __builtin_amdgcn_mfma_f32_16x16x32_bf16(af1, b1.v, d, 0, 0, 0);
      const int colb = t * 16 + c;
#pragma unroll
      for (int i = 0; i < 4; ++i)
        g1s[(rw + i) * 328 + colb] = f2bf(fmaxf(d[i], 0.f));
    }
  }
  __syncthreads();

  // ---- stage 3: GEMM2 + fused head dot ----
  const int wr = w >> 1, wc = w & 1;
  float xacc[4][4];
#pragma unroll
  for (int a0 = 0; a0 < 4; ++a0)
#pragma unroll
    for (int a1 = 0; a1 < 4; ++a1) xacc[a0][a1] = 0.f;

  for (int tp = 0; tp < 5; ++tp) {
    const int t0 = wc * 10 + tp * 2;   // this wave's tile pair
    f32x4 acc[4][2];
#pragma unroll
    for (int a0 = 0; a0 < 4; ++a0) {
      acc[a0][0] = {0.f, 0.f, 0.f, 0.f};
      acc[a0][1] = {0.f, 0.f, 0.f, 0.f};
    }
    for (int s = 0; s < 10; ++s) {
      V16 b0, b1;
      b0.u = b2p[((t0 + 0) * 10 + s) * 64 + lane];
      b1.u = b2p[((t0 + 1) * 10 + s) * 64 + lane];
      const int k0 = s * 32 + quad * 8;
#pragma unroll
      for (int rbi = 0; rbi < 4; ++rbi) {
        const int row = 64 * wr + 16 * rbi + c;
        V16 av;
        av.u = *(const uint4*)&g1s[row * 328 + k0];
        acc[rbi][0] = __builtin_amdgcn_mfma_f32_16x16x32_bf16(av.v, b0.v, acc[rbi][0], 0, 0, 0);
        acc[rbi][1] = __builtin_amdgcn_mfma_f32_16x16x32_bf16(av.v, b1.v, acc[rbi][1], 0, 0, 0);
      }
    }
#pragma unroll
    for (int tt = 0; tt < 2; ++tt) {
      const int col = (t0 + tt) * 16 + c;
      const bool inb = (col < 300);
      const float bias = inb ? g2b[col] : 0.f;
#pragma unroll
      for (int rbi = 0; rbi < 4; ++rbi) {
        const int dr = d0 + 64 * wr + 16 * rbi + quad * 4;
#pragma unroll
        for (int i = 0; i < 4; ++i) {
          const float g2v = fmaxf(acc[rbi][tt][i] + bias, 0.f);
          const float h = inb ? hw[(dr + i) * 300 + col] : 0.f;
          xacc[rbi][i] += g2v * h;
        }
      }
    }
  }

  // butterfly-reduce across the 16 lanes of each quad group (cols)
#pragma unroll
  for (int rbi = 0; rbi < 4; ++rbi)
#pragma unroll
    for (int i = 0; i < 4; ++i) {
      float v = xacc[rbi][i];
      v += __shfl_xor(v, 1);
      v += __shfl_xor(v, 2);
      v += __shfl_xor(v, 4);
      v += __shfl_xor(v, 8);
      xacc[rbi][i] = v;
    }
  if (c < 4) {
#pragma unroll
    for (int rbi = 0; rbi < 4; ++rbi) {
      float v = xacc[rbi][0];
      v = (c == 1) ? xacc[rbi][1] : v;
      v = (c == 2) ? xacc[rbi][2] : v;
      v = (c == 3) ? xacc[rbi][3] : v;
      xred[wc][64 * wr + 16 * rbi + 4 * quad + c] = v;
    }
  }
  __syncthreads();
  if (tid < 128) {
    const float v = xred[0][tid] + xred[1][tid] + hb[d0 + tid];
    xout[r0 + tid] = v;
  }
}

extern "C" void kernel_launch(void* const* d_in, const int* in_sizes, int n_in,
                              void* d_out, int out_size, void* d_ws, size_t ws_size,
                              hipStream_t stream) {
  const float* x   = (const float*)d_in[0];
  const float* eps = (const float*)d_in[1];
  const float* W   = (const float*)d_in[2];
  const float* e1w = (const float*)d_in[3];
  const float* e1b = (const float*)d_in[4];
  const float* e2w = (const float*)d_in[5];
  const float* e2b = (const float*)d_in[6];
  const float* zmw = (const float*)d_in[7];
  const float* zmb = (const float*)d_in[8];
  const float* zvw = (const float*)d_in[9];
  const float* zvb = (const float*)d_in[10];
  const float* g1w = (const float*)d_in[11];
  const float* g2w = (const float*)d_in[12];
  const float* g2b = (const float*)d_in[13];
  const float* hw  = (const float*)d_in[14];
  const float* hb  = (const float*)d_in[15];
  float* out = (float*)d_out;
  u16* ws  = (u16*)d_ws;

  pack_kernel<<<60, 256, 0, stream>>>(g1w, g2w, ws);
  enc_kernel<<<256, 320, 0, stream>>>(x, eps, e1w, e1b, e2w, e2b,
                                      zmw, zmb, zvw, zvb, out);
  dec_kernel<<<1024, 256, 0, stream>>>(out + Z_OFF, W,
                                       (const uint4*)ws, ((const uint4*)ws) + 2560,
                                       g2b, hw, hb, out);
}

// Round 3
// 221.427 us; speedup vs baseline: 1.0018x; 1.0018x over previous
//
#include <hip/hip_runtime.h>

typedef unsigned short u16;
typedef unsigned int u32;

typedef __bf16 bf16x8 __attribute__((ext_vector_type(8)));
typedef float f32x4 __attribute__((ext_vector_type(4)));

union V16 { uint4 u; bf16x8 v; u16 s[8]; };
union F4  { float4 v; float f[4]; };

__device__ __forceinline__ float bf2f(u16 a) {
  union { u32 u; float f; } c; c.u = ((u32)a) << 16; return c.f;
}
__device__ __forceinline__ u16 f2bf(float f) {
  union { float f; u32 u; } c; c.f = f;
  u32 u = c.u;
  u += 0x7fffu + ((u >> 16) & 1u);   // RNE
  return (u16)(u >> 16);
}

#define Z_OFF   131072
#define ZM_OFF  147456
#define ZLV_OFF 163840

// ws layout in uint4 fragments; b-frag element j of lane:
//   B[k = s*32 + (lane>>4)*8 + j][n = t*16 + (lane&15)],  frag id = (t*S + s)*64 + lane
// All sources are [n][k] row-major.
#define B1_OFF 0        // gen1_w: t<20 (N=320), s<2  (K=64)
#define B2_OFF 2560     // gen2_w: t<20, s<10 (K=320, src 300)
#define E1_OFF 15360    // enc1_w: t<20, s<16 (K=512)
#define E2_OFF 35840    // enc2_w: t<20, s<10
#define ZMP_OFF 48640   // zm_w: t<4 (N=64), s<10
#define ZVP_OFF 51200   // zv_w: t<4, s<10
#define PACK_TOTAL 53760

__device__ __forceinline__ void pack_one(const float* __restrict__ src,
                                         int t, int s, int lane,
                                         int Nsrc, int Ksrc, int rowlen,
                                         uint4* __restrict__ dst) {
  const int n = t * 16 + (lane & 15);
  const int k0 = s * 32 + ((lane >> 4) << 3);
  V16 v;
#pragma unroll
  for (int j = 0; j < 8; ++j) {
    const int k = k0 + j;
    v.s[j] = (n < Nsrc && k < Ksrc) ? f2bf(src[n * rowlen + k]) : (u16)0;
  }
  *dst = v.u;
}

__global__ __launch_bounds__(256) void pack_kernel(
    const float* __restrict__ g1w, const float* __restrict__ g2w,
    const float* __restrict__ e1w, const float* __restrict__ e2w,
    const float* __restrict__ zmw, const float* __restrict__ zvw,
    uint4* __restrict__ ws4) {
  const int idx = blockIdx.x * 256 + threadIdx.x;
  if (idx >= PACK_TOTAL) return;
  const int lane = idx & 63;
  if (idx < B2_OFF) {
    const int f = (idx - B1_OFF) >> 6;
    pack_one(g1w, f >> 1, f & 1, lane, 300, 64, 64, ws4 + idx);
  } else if (idx < E1_OFF) {
    const int f = (idx - B2_OFF) >> 6;
    pack_one(g2w, f / 10, f % 10, lane, 300, 300, 300, ws4 + idx);
  } else if (idx < E2_OFF) {
    const int f = (idx - E1_OFF) >> 6;
    pack_one(e1w, f >> 4, f & 15, lane, 300, 512, 512, ws4 + idx);
  } else if (idx < ZMP_OFF) {
    const int f = (idx - E2_OFF) >> 6;
    pack_one(e2w, f / 10, f % 10, lane, 300, 300, 300, ws4 + idx);
  } else if (idx < ZVP_OFF) {
    const int f = (idx - ZMP_OFF) >> 6;
    pack_one(zmw, f / 10, f % 10, lane, 64, 300, 300, ws4 + idx);
  } else {
    const int f = (idx - ZVP_OFF) >> 6;
    pack_one(zvw, f / 10, f % 10, lane, 64, 300, 300, ws4 + idx);
  }
}

// ---------------------------------------------------------------------------
// Encoder (MFMA): 16 WGs x 256 thr; each WG does 16 batch rows through all 4
// layers. fp32 accum; h1/h2 round-trip LDS in A-operand layout (stride 328).
// ---------------------------------------------------------------------------
__global__ __launch_bounds__(256) void enc_kernel(
    const float* __restrict__ x, const float* __restrict__ eps,
    const uint4* __restrict__ e1p, const float* __restrict__ e1b,
    const uint4* __restrict__ e2p, const float* __restrict__ e2b,
    const uint4* __restrict__ zmp, const float* __restrict__ zmb,
    const uint4* __restrict__ zvp, const float* __restrict__ zvb,
    float* __restrict__ out) {
  __shared__ u16 h1s[16 * 328];
  __shared__ u16 h2s[16 * 328];
  const int bi0 = blockIdx.x * 16;
  const int tid = threadIdx.x;
  const int w = tid >> 6, lane = tid & 63, q = lane >> 4, c = lane & 15;

  // A-frags for layer1 from x (bf16-converted)
  bf16x8 af[16];
#pragma unroll
  for (int s = 0; s < 16; ++s) {
    const float* px = x + (bi0 + c) * 512 + s * 32 + q * 8;
    F4 a, b; a.v = *(const float4*)px; b.v = *(const float4*)(px + 4);
    V16 m;
#pragma unroll
    for (int j = 0; j < 4; ++j) { m.s[j] = f2bf(a.f[j]); m.s[4 + j] = f2bf(b.f[j]); }
    af[s] = m.v;
  }
  // GEMM1: wave w covers n-tiles 5w..5w+4
  f32x4 acc[5];
#pragma unroll
  for (int tt = 0; tt < 5; ++tt) acc[tt] = {0.f, 0.f, 0.f, 0.f};
  for (int s = 0; s < 16; ++s) {
#pragma unroll
    for (int tt = 0; tt < 5; ++tt) {
      V16 b; b.u = e1p[((w * 5 + tt) * 16 + s) * 64 + lane];
      acc[tt] = __builtin_amdgcn_mfma_f32_16x16x32_bf16(af[s], b.v, acc[tt], 0, 0, 0);
    }
  }
#pragma unroll
  for (int tt = 0; tt < 5; ++tt) {
    const int col = (w * 5 + tt) * 16 + c;
    const float bias = (col < 300) ? e1b[col] : 0.f;
#pragma unroll
    for (int i = 0; i < 4; ++i)
      h1s[(4 * q + i) * 328 + col] = (col < 300) ? f2bf(fmaxf(acc[tt][i] + bias, 0.f)) : (u16)0;
  }
  __syncthreads();
  // GEMM2
#pragma unroll
  for (int tt = 0; tt < 5; ++tt) acc[tt] = {0.f, 0.f, 0.f, 0.f};
  for (int s = 0; s < 10; ++s) {
    V16 a; a.u = *(const uint4*)&h1s[c * 328 + s * 32 + q * 8];
#pragma unroll
    for (int tt = 0; tt < 5; ++tt) {
      V16 b; b.u = e2p[((w * 5 + tt) * 10 + s) * 64 + lane];
      acc[tt] = __builtin_amdgcn_mfma_f32_16x16x32_bf16(a.v, b.v, acc[tt], 0, 0, 0);
    }
  }
#pragma unroll
  for (int tt = 0; tt < 5; ++tt) {
    const int col = (w * 5 + tt) * 16 + c;
    const float bias = (col < 300) ? e2b[col] : 0.f;
#pragma unroll
    for (int i = 0; i < 4; ++i)
      h2s[(4 * q + i) * 328 + col] = (col < 300) ? f2bf(fmaxf(acc[tt][i] + bias, 0.f)) : (u16)0;
  }
  __syncthreads();
  // Heads: wave w covers z-cols 16w..16w+15 for both zm and zv
  f32x4 am = {0.f, 0.f, 0.f, 0.f}, av = {0.f, 0.f, 0.f, 0.f};
  for (int s = 0; s < 10; ++s) {
    V16 a; a.u = *(const uint4*)&h2s[c * 328 + s * 32 + q * 8];
    V16 bm, bv;
    bm.u = zmp[(w * 10 + s) * 64 + lane];
    bv.u = zvp[(w * 10 + s) * 64 + lane];
    am = __builtin_amdgcn_mfma_f32_16x16x32_bf16(a.v, bm.v, am, 0, 0, 0);
    av = __builtin_amdgcn_mfma_f32_16x16x32_bf16(a.v, bv.v, av, 0, 0, 0);
  }
  const int col = w * 16 + c;
#pragma unroll
  for (int i = 0; i < 4; ++i) {
    const int row = bi0 + 4 * q + i;
    const float zm = am[i] + zmb[col];
    const float zlv = av[i] + zvb[col];
    const float zz = zm + eps[row * 64 + col] * expf(0.5f * zlv);
    out[Z_OFF   + row * 64 + col] = zz;
    out[ZM_OFF  + row * 64 + col] = zm;
    out[ZLV_OFF + row * 64 + col] = zlv;
  }
}

// ---------------------------------------------------------------------------
// Fused decoder. 1024 WGs x 640 thr (10 waves). 128 rows/WG (one b).
// Wave w owns n-tiles {2w,2w+1} across ALL 128 rows (8 rowtiles) so every
// b-fragment is read exactly once per WG. Stage 2 uses the identity
// g1 = bf16(W_rows) @ (diag(z) * gen1^T): A = W (L1-resident), B = z-scaled
// b1p frags. g1 -> bf16 LDS tile [128][328]. Stage 3: GEMM2 + fused head dot,
// butterfly + cross-wave LDS reduction.
// ---------------------------------------------------------------------------
__global__ __launch_bounds__(640) void dec_kernel(
    const float* __restrict__ z,  // [256][64] (fp32, in d_out)
    const float* __restrict__ W,  // [512][64]
    const uint4* __restrict__ b1p,
    const uint4* __restrict__ b2p,
    const float* __restrict__ g2b,  // [300]
    const float* __restrict__ hw,   // [512][300]
    const float* __restrict__ hb,   // [512]
    float* __restrict__ xout)       // [256*512]
{
  __shared__ u16 g1s[128 * 328];    // 83,968 B
  __shared__ float xred[10][128];   // 5,120 B

  const int wg = blockIdx.x;
  const int r0 = wg << 7;
  const int bi = r0 >> 9;
  const int d0 = r0 & 511;
  const int tid = threadIdx.x;
  const int w = tid >> 6;
  const int lane = tid & 63;
  const int q = lane >> 4;
  const int c = lane & 15;
  const int ta = 2 * w;

  const float* zrow = z + bi * 64;

  // ---- stage 2: g1 for tiles ta, ta+1, all 128 rows ----
  {
    bf16x8 af[8][2];
#pragma unroll
    for (int rt = 0; rt < 8; ++rt)
#pragma unroll
      for (int kf = 0; kf < 2; ++kf) {
        const float* p = W + (d0 + rt * 16 + c) * 64 + kf * 32 + q * 8;
        F4 a, b; a.v = *(const float4*)p; b.v = *(const float4*)(p + 4);
        V16 m;
#pragma unroll
        for (int j = 0; j < 4; ++j) { m.s[j] = f2bf(a.f[j]); m.s[4 + j] = f2bf(b.f[j]); }
        af[rt][kf] = m.v;
      }
    bf16x8 bz[2][2];
#pragma unroll
    for (int kf = 0; kf < 2; ++kf) {
      F4 z0, z1;
      z0.v = *(const float4*)(zrow + kf * 32 + q * 8);
      z1.v = *(const float4*)(zrow + kf * 32 + q * 8 + 4);
#pragma unroll
      for (int tt = 0; tt < 2; ++tt) {
        V16 r; r.u = b1p[((ta + tt) * 2 + kf) * 64 + lane];
        V16 m;
#pragma unroll
        for (int j = 0; j < 4; ++j) {
          m.s[j]     = f2bf(bf2f(r.s[j])     * z0.f[j]);
          m.s[4 + j] = f2bf(bf2f(r.s[4 + j]) * z1.f[j]);
        }
        bz[tt][kf] = m.v;
      }
    }
    f32x4 acc[2][8];
#pragma unroll
    for (int tt = 0; tt < 2; ++tt)
#pragma unroll
      for (int rt = 0; rt < 8; ++rt) acc[tt][rt] = {0.f, 0.f, 0.f, 0.f};
#pragma unroll
    for (int kf = 0; kf < 2; ++kf)
#pragma unroll
      for (int rt = 0; rt < 8; ++rt) {
        acc[0][rt] = __builtin_amdgcn_mfma_f32_16x16x32_bf16(af[rt][kf], bz[0][kf], acc[0][rt], 0, 0, 0);
        acc[1][rt] = __builtin_amdgcn_mfma_f32_16x16x32_bf16(af[rt][kf], bz[1][kf], acc[1][rt], 0, 0, 0);
      }
#pragma unroll
    for (int tt = 0; tt < 2; ++tt)
#pragma unroll
      for (int rt = 0; rt < 8; ++rt)
#pragma unroll
        for (int i = 0; i < 4; ++i)
          g1s[(rt * 16 + 4 * q + i) * 328 + (ta + tt) * 16 + c] = f2bf(fmaxf(acc[tt][rt][i], 0.f));
  }
  __syncthreads();

  // ---- stage 3: GEMM2 (tiles ta, ta+1) + fused head dot ----
  f32x4 a3[2][8];
#pragma unroll
  for (int tt = 0; tt < 2; ++tt)
#pragma unroll
    for (int rt = 0; rt < 8; ++rt) a3[tt][rt] = {0.f, 0.f, 0.f, 0.f};
  for (int s = 0; s < 10; ++s) {
    V16 b0, b1;
    b0.u = b2p[((ta + 0) * 10 + s) * 64 + lane];
    b1.u = b2p[((ta + 1) * 10 + s) * 64 + lane];
#pragma unroll
    for (int rt = 0; rt < 8; ++rt) {
      V16 a; a.u = *(const uint4*)&g1s[(rt * 16 + c) * 328 + s * 32 + q * 8];
      a3[0][rt] = __builtin_amdgcn_mfma_f32_16x16x32_bf16(a.v, b0.v, a3[0][rt], 0, 0, 0);
      a3[1][rt] = __builtin_amdgcn_mfma_f32_16x16x32_bf16(a.v, b1.v, a3[1][rt], 0, 0, 0);
    }
  }
  float xacc[8][4];
#pragma unroll
  for (int rt = 0; rt < 8; ++rt)
#pragma unroll
    for (int i = 0; i < 4; ++i) xacc[rt][i] = 0.f;
#pragma unroll
  for (int tt = 0; tt < 2; ++tt) {
    const int col = (ta + tt) * 16 + c;
    const bool inb = (col < 300);
    const float bias = inb ? g2b[col] : 0.f;
#pragma unroll
    for (int rt = 0; rt < 8; ++rt)
#pragma unroll
      for (int i = 0; i < 4; ++i) {
        const float g2v = fmaxf(a3[tt][rt][i] + bias, 0.f);
        const float h = inb ? hw[(d0 + rt * 16 + 4 * q + i) * 300 + col] : 0.f;
        xacc[rt][i] += g2v * h;
      }
  }
#pragma unroll
  for (int rt = 0; rt < 8; ++rt)
#pragma unroll
    for (int i = 0; i < 4; ++i) {
      float v = xacc[rt][i];
      v += __shfl_xor(v, 1);
      v += __shfl_xor(v, 2);
      v += __shfl_xor(v, 4);
      v += __shfl_xor(v, 8);
      xacc[rt][i] = v;
    }
  if (c < 4) {
#pragma unroll
    for (int rt = 0; rt < 8; ++rt) {
      float v = xacc[rt][0];
      v = (c == 1) ? xacc[rt][1] : v;
      v = (c == 2) ? xacc[rt][2] : v;
      v = (c == 3) ? xacc[rt][3] : v;
      xred[w][rt * 16 + 4 * q + c] = v;
    }
  }
  __syncthreads();
  if (tid < 128) {
    float v = hb[d0 + tid];
#pragma unroll
    for (int ww = 0; ww < 10; ++ww) v += xred[ww][tid];
    xout[r0 + tid] = v;
  }
}

extern "C" void kernel_launch(void* const* d_in, const int* in_sizes, int n_in,
                              void* d_out, int out_size, void* d_ws, size_t ws_size,
                              hipStream_t stream) {
  const float* x   = (const float*)d_in[0];
  const float* eps = (const float*)d_in[1];
  const float* W   = (const float*)d_in[2];
  const float* e1w = (const float*)d_in[3];
  const float* e1b = (const float*)d_in[4];
  const float* e2w = (const float*)d_in[5];
  const float* e2b = (const float*)d_in[6];
  const float* zmw = (const float*)d_in[7];
  const float* zmb = (const float*)d_in[8];
  const float* zvw = (const float*)d_in[9];
  const float* zvb = (const float*)d_in[10];
  const float* g1w = (const float*)d_in[11];
  const float* g2w = (const float*)d_in[12];
  const float* g2b = (const float*)d_in[13];
  const float* hw  = (const float*)d_in[14];
  const float* hb  = (const float*)d_in[15];
  float* out = (float*)d_out;
  uint4* ws4 = (uint4*)d_ws;

  pack_kernel<<<(PACK_TOTAL + 255) / 256, 256, 0, stream>>>(g1w, g2w, e1w, e2w, zmw, zvw, ws4);
  enc_kernel<<<16, 256, 0, stream>>>(x, eps,
                                     ws4 + E1_OFF, e1b, ws4 + E2_OFF, e2b,
                                     ws4 + ZMP_OFF, zmb, ws4 + ZVP_OFF, zvb, out);
  dec_kernel<<<1024, 640, 0, stream>>>(out + Z_OFF, W,
                                       ws4 + B1_OFF, ws4 + B2_OFF,
                                       g2b, hw, hb, out);
}

// Round 4
// 194.265 us; speedup vs baseline: 1.1419x; 1.1398x over previous
//
#include <hip/hip_runtime.h>

typedef unsigned short u16;
typedef unsigned int u32;

typedef __bf16 bf16x8 __attribute__((ext_vector_type(8)));
typedef float f32x4 __attribute__((ext_vector_type(4)));

union V16 { uint4 u; bf16x8 v; u16 s[8]; };
union F4  { float4 v; float f[4]; };

__device__ __forceinline__ float bf2f(u16 a) {
  union { u32 u; float f; } c; c.u = ((u32)a) << 16; return c.f;
}
__device__ __forceinline__ u16 f2bf(float f) {
  union { float f; u32 u; } c; c.f = f;
  u32 u = c.u;
  u += 0x7fffu + ((u >> 16) & 1u);   // RNE
  return (u16)(u >> 16);
}

#define Z_OFF   131072
#define ZM_OFF  147456
#define ZLV_OFF 163840

// ws layout in uint4 fragments; b-frag element j of lane:
//   B[k = s*32 + (lane>>4)*8 + j][n = t*16 + (lane&15)],  frag id = (t*S + s)*64 + lane
// All sources are [n][k] row-major.
#define B1_OFF 0        // gen1_w: t<20 (N=320), s<2  (K=64)
#define B2_OFF 2560     // gen2_w: t<20, s<10 (K=320, src 300)
#define E1_OFF 15360    // enc1_w: t<20, s<16 (K=512)
#define E2_OFF 35840    // enc2_w: t<20, s<10
#define ZMP_OFF 48640   // zm_w: t<4 (N=64), s<10
#define ZVP_OFF 51200   // zv_w: t<4, s<10
#define PACK_TOTAL 53760

__device__ __forceinline__ void pack_one(const float* __restrict__ src,
                                         int t, int s, int lane,
                                         int Nsrc, int Ksrc, int rowlen,
                                         uint4* __restrict__ dst) {
  const int n = t * 16 + (lane & 15);
  const int k0 = s * 32 + ((lane >> 4) << 3);
  V16 v;
#pragma unroll
  for (int j = 0; j < 8; ++j) {
    const int k = k0 + j;
    v.s[j] = (n < Nsrc && k < Ksrc) ? f2bf(src[n * rowlen + k]) : (u16)0;
  }
  *dst = v.u;
}

__global__ __launch_bounds__(256) void pack_kernel(
    const float* __restrict__ g1w, const float* __restrict__ g2w,
    const float* __restrict__ e1w, const float* __restrict__ e2w,
    const float* __restrict__ zmw, const float* __restrict__ zvw,
    uint4* __restrict__ ws4) {
  const int idx = blockIdx.x * 256 + threadIdx.x;
  if (idx >= PACK_TOTAL) return;
  const int lane = idx & 63;
  if (idx < B2_OFF) {
    const int f = (idx - B1_OFF) >> 6;
    pack_one(g1w, f >> 1, f & 1, lane, 300, 64, 64, ws4 + idx);
  } else if (idx < E1_OFF) {
    const int f = (idx - B2_OFF) >> 6;
    pack_one(g2w, f / 10, f % 10, lane, 300, 300, 300, ws4 + idx);
  } else if (idx < E2_OFF) {
    const int f = (idx - E1_OFF) >> 6;
    pack_one(e1w, f >> 4, f & 15, lane, 300, 512, 512, ws4 + idx);
  } else if (idx < ZMP_OFF) {
    const int f = (idx - E2_OFF) >> 6;
    pack_one(e2w, f / 10, f % 10, lane, 300, 300, 300, ws4 + idx);
  } else if (idx < ZVP_OFF) {
    const int f = (idx - ZMP_OFF) >> 6;
    pack_one(zmw, f / 10, f % 10, lane, 64, 300, 300, ws4 + idx);
  } else {
    const int f = (idx - ZVP_OFF) >> 6;
    pack_one(zvw, f / 10, f % 10, lane, 64, 300, 300, ws4 + idx);
  }
}

// ---------------------------------------------------------------------------
// Encoder (MFMA): 16 WGs x 640 thr (10 waves); each WG does 16 batch rows.
// Wave w owns n-tiles {2w, 2w+1} in GEMM1/GEMM2; waves 0-7 do the 8 head
// tiles (4 zm + 4 zv). fp32 accum; h1/h2 in LDS A-layout (stride 328).
// ---------------------------------------------------------------------------
__global__ __launch_bounds__(640, 3) void enc_kernel(
    const float* __restrict__ x, const float* __restrict__ eps,
    const uint4* __restrict__ e1p, const float* __restrict__ e1b,
    const uint4* __restrict__ e2p, const float* __restrict__ e2b,
    const uint4* __restrict__ zmp, const float* __restrict__ zmb,
    const uint4* __restrict__ zvp, const float* __restrict__ zvb,
    float* __restrict__ out) {
  __shared__ u16 h1s[16 * 328];
  __shared__ u16 h2s[16 * 328];
  __shared__ float zms[1024], zlvs[1024];
  const int bi0 = blockIdx.x * 16;
  const int tid = threadIdx.x;
  const int w = tid >> 6, lane = tid & 63, q = lane >> 4, c = lane & 15;

  // A-frags for layer1 from x (bf16-converted); shared across this wave's tiles
  bf16x8 af[16];
#pragma unroll
  for (int s = 0; s < 16; ++s) {
    const float* px = x + (bi0 + c) * 512 + s * 32 + q * 8;
    F4 a, b; a.v = *(const float4*)px; b.v = *(const float4*)(px + 4);
    V16 m;
#pragma unroll
    for (int j = 0; j < 4; ++j) { m.s[j] = f2bf(a.f[j]); m.s[4 + j] = f2bf(b.f[j]); }
    af[s] = m.v;
  }
  // GEMM1: tiles 2w, 2w+1
  f32x4 acc0 = {0.f, 0.f, 0.f, 0.f}, acc1 = {0.f, 0.f, 0.f, 0.f};
  for (int s = 0; s < 16; ++s) {
    V16 b0, b1;
    b0.u = e1p[((2 * w + 0) * 16 + s) * 64 + lane];
    b1.u = e1p[((2 * w + 1) * 16 + s) * 64 + lane];
    acc0 = __builtin_amdgcn_mfma_f32_16x16x32_bf16(af[s], b0.v, acc0, 0, 0, 0);
    acc1 = __builtin_amdgcn_mfma_f32_16x16x32_bf16(af[s], b1.v, acc1, 0, 0, 0);
  }
#pragma unroll
  for (int tt = 0; tt < 2; ++tt) {
    const f32x4 acc = tt ? acc1 : acc0;
    const int col = (2 * w + tt) * 16 + c;
    const float bias = (col < 300) ? e1b[col] : 0.f;
#pragma unroll
    for (int i = 0; i < 4; ++i)
      h1s[(4 * q + i) * 328 + col] = (col < 300) ? f2bf(fmaxf(acc[i] + bias, 0.f)) : (u16)0;
  }
  __syncthreads();
  // GEMM2: tiles 2w, 2w+1
  acc0 = {0.f, 0.f, 0.f, 0.f}; acc1 = {0.f, 0.f, 0.f, 0.f};
  for (int s = 0; s < 10; ++s) {
    V16 a; a.u = *(const uint4*)&h1s[c * 328 + s * 32 + q * 8];
    V16 b0, b1;
    b0.u = e2p[((2 * w + 0) * 10 + s) * 64 + lane];
    b1.u = e2p[((2 * w + 1) * 10 + s) * 64 + lane];
    acc0 = __builtin_amdgcn_mfma_f32_16x16x32_bf16(a.v, b0.v, acc0, 0, 0, 0);
    acc1 = __builtin_amdgcn_mfma_f32_16x16x32_bf16(a.v, b1.v, acc1, 0, 0, 0);
  }
#pragma unroll
  for (int tt = 0; tt < 2; ++tt) {
    const f32x4 acc = tt ? acc1 : acc0;
    const int col = (2 * w + tt) * 16 + c;
    const float bias = (col < 300) ? e2b[col] : 0.f;
#pragma unroll
    for (int i = 0; i < 4; ++i)
      h2s[(4 * q + i) * 328 + col] = (col < 300) ? f2bf(fmaxf(acc[i] + bias, 0.f)) : (u16)0;
  }
  __syncthreads();
  // Heads: waves 0-3 -> zm tiles 0-3; waves 4-7 -> zv tiles 0-3
  if (w < 8) {
    const bool is_m = (w < 4);
    const int t = w & 3;
    const uint4* hp = is_m ? zmp : zvp;
    f32x4 a4 = {0.f, 0.f, 0.f, 0.f};
    for (int s = 0; s < 10; ++s) {
      V16 a; a.u = *(const uint4*)&h2s[c * 328 + s * 32 + q * 8];
      V16 b; b.u = hp[(t * 10 + s) * 64 + lane];
      a4 = __builtin_amdgcn_mfma_f32_16x16x32_bf16(a.v, b.v, a4, 0, 0, 0);
    }
    const int col = t * 16 + c;
    const float bias = is_m ? zmb[col] : zvb[col];
    float* dst = is_m ? zms : zlvs;
#pragma unroll
    for (int i = 0; i < 4; ++i) dst[(4 * q + i) * 64 + col] = a4[i] + bias;
  }
  __syncthreads();
  for (int idx = tid; idx < 1024; idx += 640) {
    const int row = idx >> 6, col = idx & 63;
    const int gi = (bi0 + row) * 64 + col;
    const float zm = zms[idx], zlv = zlvs[idx];
    const float zz = zm + eps[gi] * expf(0.5f * zlv);
    out[Z_OFF + gi] = zz;
    out[ZM_OFF + gi] = zm;
    out[ZLV_OFF + gi] = zlv;
  }
}

// ---------------------------------------------------------------------------
// Fused decoder. 1024 WGs x 640 thr (10 waves). 128 rows/WG (one b).
// Wave grid 5x2: u = w>>1 owns n-tiles {4u..4u+3}, v = w&1 owns 64-row half.
// Stage 2: g1 = bf16(W_rows) @ (diag(z)*gen1^T), A-frags loaded per rowtile
// (no big register arrays -> no spills). g1 -> bf16 LDS [128][328].
// Stage 3: GEMM2 (a3[4][4] = 64 VGPRs) + fused head dot; butterfly +
// cross-u LDS reduction. __launch_bounds__(640,3) caps VGPR ~170.
// ---------------------------------------------------------------------------
__global__ __launch_bounds__(640, 3) void dec_kernel(
    const float* __restrict__ z,  // [256][64] (fp32, in d_out)
    const float* __restrict__ W,  // [512][64]
    const uint4* __restrict__ b1p,
    const uint4* __restrict__ b2p,
    const float* __restrict__ g2b,  // [300]
    const float* __restrict__ hw,   // [512][300]
    const float* __restrict__ hb,   // [512]
    float* __restrict__ xout)       // [256*512]
{
  __shared__ u16 g1s[128 * 328];    // 83,968 B
  __shared__ float xred[5][128];    // 2,560 B

  const int wg = blockIdx.x;
  const int r0 = wg << 7;
  const int bi = r0 >> 9;
  const int d0 = r0 & 511;
  const int tid = threadIdx.x;
  const int w = tid >> 6;
  const int lane = tid & 63;
  const int q = lane >> 4;
  const int c = lane & 15;
  const int u = w >> 1;     // 0..4: n-tile group (tiles 4u..4u+3)
  const int v = w & 1;      // 0..1: row half (rows v*64..v*64+63)

  const float* zrow = z + bi * 64;

  // ---- stage 2: g1 for tiles 4u..4u+3, rows v*64..+63 ----
  bf16x8 bz[4][2];
#pragma unroll
  for (int kf = 0; kf < 2; ++kf) {
    F4 z0, z1;
    z0.v = *(const float4*)(zrow + kf * 32 + q * 8);
    z1.v = *(const float4*)(zrow + kf * 32 + q * 8 + 4);
#pragma unroll
    for (int tt = 0; tt < 4; ++tt) {
      V16 r; r.u = b1p[((4 * u + tt) * 2 + kf) * 64 + lane];
      V16 m;
#pragma unroll
      for (int j = 0; j < 4; ++j) {
        m.s[j]     = f2bf(bf2f(r.s[j])     * z0.f[j]);
        m.s[4 + j] = f2bf(bf2f(r.s[4 + j]) * z1.f[j]);
      }
      bz[tt][kf] = m.v;
    }
  }
  for (int rt = 0; rt < 4; ++rt) {
    const int rowA = v * 64 + rt * 16 + c;
    const float* p = W + (d0 + rowA) * 64 + q * 8;
    bf16x8 af0, af1;
    {
      F4 a, b; V16 m;
      a.v = *(const float4*)p; b.v = *(const float4*)(p + 4);
#pragma unroll
      for (int j = 0; j < 4; ++j) { m.s[j] = f2bf(a.f[j]); m.s[4 + j] = f2bf(b.f[j]); }
      af0 = m.v;
      a.v = *(const float4*)(p + 32); b.v = *(const float4*)(p + 36);
#pragma unroll
      for (int j = 0; j < 4; ++j) { m.s[j] = f2bf(a.f[j]); m.s[4 + j] = f2bf(b.f[j]); }
      af1 = m.v;
    }
    f32x4 acc[4];
#pragma unroll
    for (int tt = 0; tt < 4; ++tt) acc[tt] = {0.f, 0.f, 0.f, 0.f};
#pragma unroll
    for (int tt = 0; tt < 4; ++tt) {
      acc[tt] = __builtin_amdgcn_mfma_f32_16x16x32_bf16(af0, bz[tt][0], acc[tt], 0, 0, 0);
      acc[tt] = __builtin_amdgcn_mfma_f32_16x16x32_bf16(af1, bz[tt][1], acc[tt], 0, 0, 0);
    }
    const int rwb = v * 64 + rt * 16 + 4 * q;
#pragma unroll
    for (int tt = 0; tt < 4; ++tt) {
      const int colb = (4 * u + tt) * 16 + c;
#pragma unroll
      for (int i = 0; i < 4; ++i)
        g1s[(rwb + i) * 328 + colb] = f2bf(fmaxf(acc[tt][i], 0.f));
    }
  }
  __syncthreads();

  // ---- stage 3: GEMM2 (tiles 4u..4u+3, rows v*64..+63) + fused head dot ----
  f32x4 a3[4][4];   // [tt][rt]
#pragma unroll
  for (int tt = 0; tt < 4; ++tt)
#pragma unroll
    for (int rt = 0; rt < 4; ++rt) a3[tt][rt] = {0.f, 0.f, 0.f, 0.f};
  for (int s = 0; s < 10; ++s) {
    V16 b[4];
#pragma unroll
    for (int tt = 0; tt < 4; ++tt) b[tt].u = b2p[((4 * u + tt) * 10 + s) * 64 + lane];
#pragma unroll
    for (int rt = 0; rt < 4; ++rt) {
      V16 a; a.u = *(const uint4*)&g1s[(v * 64 + rt * 16 + c) * 328 + s * 32 + q * 8];
#pragma unroll
      for (int tt = 0; tt < 4; ++tt)
        a3[tt][rt] = __builtin_amdgcn_mfma_f32_16x16x32_bf16(a.v, b[tt].v, a3[tt][rt], 0, 0, 0);
    }
  }
  float xacc[4][4];   // [rt][i]
#pragma unroll
  for (int rt = 0; rt < 4; ++rt)
#pragma unroll
    for (int i = 0; i < 4; ++i) xacc[rt][i] = 0.f;
#pragma unroll
  for (int tt = 0; tt < 4; ++tt) {
    const int col = (4 * u + tt) * 16 + c;
    const bool inb = (col < 300);
    const float bias = inb ? g2b[col] : 0.f;
#pragma unroll
    for (int rt = 0; rt < 4; ++rt)
#pragma unroll
      for (int i = 0; i < 4; ++i) {
        const float g2v = fmaxf(a3[tt][rt][i] + bias, 0.f);
        const float h = inb ? hw[(d0 + v * 64 + rt * 16 + 4 * q + i) * 300 + col] : 0.f;
        xacc[rt][i] += g2v * h;
      }
  }
#pragma unroll
  for (int rt = 0; rt < 4; ++rt)
#pragma unroll
    for (int i = 0; i < 4; ++i) {
      float t = xacc[rt][i];
      t += __shfl_xor(t, 1);
      t += __shfl_xor(t, 2);
      t += __shfl_xor(t, 4);
      t += __shfl_xor(t, 8);
      xacc[rt][i] = t;
    }
  if (c < 4) {
#pragma unroll
    for (int rt = 0; rt < 4; ++rt) {
      float t = xacc[rt][0];
      t = (c == 1) ? xacc[rt][1] : t;
      t = (c == 2) ? xacc[rt][2] : t;
      t = (c == 3) ? xacc[rt][3] : t;
      xred[u][v * 64 + rt * 16 + 4 * q + c] = t;
    }
  }
  __syncthreads();
  if (tid < 128) {
    float t = hb[d0 + tid];
#pragma unroll
    for (int uu = 0; uu < 5; ++uu) t += xred[uu][tid];
    xout[r0 + tid] = t;
  }
}

extern "C" void kernel_launch(void* const* d_in, const int* in_sizes, int n_in,
                              void* d_out, int out_size, void* d_ws, size_t ws_size,
                              hipStream_t stream) {
  const float* x   = (const float*)d_in[0];
  const float* eps = (const float*)d_in[1];
  const float* W   = (const float*)d_in[2];
  const float* e1w = (const float*)d_in[3];
  const float* e1b = (const float*)d_in[4];
  const float* e2w = (const float*)d_in[5];
  const float* e2b = (const float*)d_in[6];
  const float* zmw = (const float*)d_in[7];
  const float* zmb = (const float*)d_in[8];
  const float* zvw = (const float*)d_in[9];
  const float* zvb = (const float*)d_in[10];
  const float* g1w = (const float*)d_in[11];
  const float* g2w = (const float*)d_in[12];
  const float* g2b = (const float*)d_in[13];
  const float* hw  = (const float*)d_in[14];
  const float* hb  = (const float*)d_in[15];
  float* out = (float*)d_out;
  uint4* ws4 = (uint4*)d_ws;

  pack_kernel<<<(PACK_TOTAL + 255) / 256, 256, 0, stream>>>(g1w, g2w, e1w, e2w, zmw, zvw, ws4);
  enc_kernel<<<16, 640, 0, stream>>>(x, eps,
                                     ws4 + E1_OFF, e1b, ws4 + E2_OFF, e2b,
                                     ws4 + ZMP_OFF, zmb, ws4 + ZVP_OFF, zvb, out);
  dec_kernel<<<1024, 640, 0, stream>>>(out + Z_OFF, W,
                                       ws4 + B1_OFF, ws4 + B2_OFF,
                                       g2b, hw, hb, out);
}

// Round 6
// 183.987 us; speedup vs baseline: 1.2057x; 1.0559x over previous
//
#include <hip/hip_runtime.h>

typedef unsigned short u16;
typedef unsigned int u32;

typedef __bf16 bf16x8 __attribute__((ext_vector_type(8)));
typedef float f32x4 __attribute__((ext_vector_type(4)));

union V16 { uint4 u; bf16x8 v; u16 s[8]; __bf16 h[8]; };
union F4  { float4 v; float f[4]; };

__device__ __forceinline__ float bf2f(u16 a) {
  union { u32 u; float f; } c; c.u = ((u32)a) << 16; return c.f;
}

#define Z_OFF   131072
#define ZM_OFF  147456
#define ZLV_OFF 163840

// ws layout in uint4 units.
// Fragment packs (b-frag elem j of lane: B[k=s*32+(lane>>4)*8+j][n=t*16+(lane&15)]):
#define B1_OFF 0        // gen1_w: t<20, s<2
#define B2_OFF 2560     // gen2_w: t<20, s<10
#define E1_OFF 15360    // enc1_w: t<20, s<16
#define E2_OFF 35840    // enc2_w: t<20, s<10
#define ZMP_OFF 48640   // zm_w: t<4, s<10
#define ZVP_OFF 51200   // zv_w: t<4, s<10
#define FRAG_TOTAL 53760
// bf16 row-major tables (uint4 = 8 bf16):
#define WB4  53760      // W bf16 [512][64]     : 4096 uint4
#define XB4  57856      // x bf16 [256][512]    : 16384 uint4
#define H1_4 74240      // h1 bf16 [256][320]   : 10240 uint4
#define H2_4 84480      // h2 bf16 [256][320]   : 10240 uint4
#define PACK_THREADS (FRAG_TOTAL + 4096 + 16384)   // 74240

__device__ __forceinline__ void pack_one(const float* __restrict__ src,
                                         int t, int s, int lane,
                                         int Nsrc, int Ksrc, int rowlen,
                                         uint4* __restrict__ dst) {
  const int n = t * 16 + (lane & 15);
  const int k0 = s * 32 + ((lane >> 4) << 3);
  V16 v;
#pragma unroll
  for (int j = 0; j < 8; ++j) {
    const int k = k0 + j;
    v.h[j] = (n < Nsrc && k < Ksrc) ? (__bf16)src[n * rowlen + k] : (__bf16)0.f;
  }
  *dst = v.u;
}

__device__ __forceinline__ void cvt8(const float* __restrict__ src, uint4* __restrict__ dst) {
  F4 a, b; a.v = *(const float4*)src; b.v = *(const float4*)(src + 4);
  V16 v;
#pragma unroll
  for (int j = 0; j < 4; ++j) { v.h[j] = (__bf16)a.f[j]; v.h[4 + j] = (__bf16)b.f[j]; }
  *dst = v.u;
}

__global__ __launch_bounds__(256) void pack_kernel(
    const float* __restrict__ g1w, const float* __restrict__ g2w,
    const float* __restrict__ e1w, const float* __restrict__ e2w,
    const float* __restrict__ zmw, const float* __restrict__ zvw,
    const float* __restrict__ W,   const float* __restrict__ x,
    uint4* __restrict__ ws4) {
  const int idx = blockIdx.x * 256 + threadIdx.x;
  if (idx >= PACK_THREADS) return;
  const int lane = idx & 63;
  if (idx < B2_OFF) {
    const int f = (idx - B1_OFF) >> 6;
    pack_one(g1w, f >> 1, f & 1, lane, 300, 64, 64, ws4 + idx);
  } else if (idx < E1_OFF) {
    const int f = (idx - B2_OFF) >> 6;
    pack_one(g2w, f / 10, f % 10, lane, 300, 300, 300, ws4 + idx);
  } else if (idx < E2_OFF) {
    const int f = (idx - E1_OFF) >> 6;
    pack_one(e1w, f >> 4, f & 15, lane, 300, 512, 512, ws4 + idx);
  } else if (idx < ZMP_OFF) {
    const int f = (idx - E2_OFF) >> 6;
    pack_one(e2w, f / 10, f % 10, lane, 300, 300, 300, ws4 + idx);
  } else if (idx < ZVP_OFF) {
    const int f = (idx - ZMP_OFF) >> 6;
    pack_one(zmw, f / 10, f % 10, lane, 64, 300, 300, ws4 + idx);
  } else if (idx < FRAG_TOTAL) {
    const int f = (idx - ZVP_OFF) >> 6;
    pack_one(zvw, f / 10, f % 10, lane, 64, 300, 300, ws4 + idx);
  } else if (idx < FRAG_TOTAL + 4096) {
    const int i = idx - FRAG_TOTAL;
    cvt8(W + i * 8, ws4 + WB4 + i);
  } else {
    const int i = idx - FRAG_TOTAL - 4096;
    cvt8(x + i * 8, ws4 + XB4 + i);
  }
}

// ---------------------------------------------------------------------------
// enc1: 320 WGs (rt 16 x nt 20) x 64 thr. h1[row][col] = relu(x @ e1w^T + b).
// A from xb (bf16), B from e1p frags, K=512 (16 steps). Writes h1 bf16
// (cols >=300 zeroed).
// ---------------------------------------------------------------------------
__global__ __launch_bounds__(64) void enc1_kernel(
    const uint4* __restrict__ xb, const uint4* __restrict__ e1p,
    const float* __restrict__ e1b, u16* __restrict__ h1) {
  const int wg = blockIdx.x;
  const int rt = wg / 20, nt = wg % 20;
  const int lane = threadIdx.x, q = lane >> 4, c = lane & 15;
  f32x4 acc = {0.f, 0.f, 0.f, 0.f};
  const int arow = rt * 16 + c;
  for (int s = 0; s < 16; ++s) {
    V16 a, b;
    a.u = xb[arow * 64 + s * 4 + q];           // 8 bf16 at k = s*32 + q*8
    b.u = e1p[(nt * 16 + s) * 64 + lane];      // e1p has S=16 k-steps per tile
    acc = __builtin_amdgcn_mfma_f32_16x16x32_bf16(a.v, b.v, acc, 0, 0, 0);
  }
  const int col = nt * 16 + c;
  const float bias = (col < 300) ? e1b[col] : 0.f;
#pragma unroll
  for (int i = 0; i < 4; ++i) {
    const int row = rt * 16 + 4 * q + i;
    V16 t; t.h[0] = (col < 300) ? (__bf16)fmaxf(acc[i] + bias, 0.f) : (__bf16)0.f;
    h1[row * 320 + col] = t.s[0];
  }
}

// enc2: same shape, K=320 (10 steps), A from h1, writes h2.
__global__ __launch_bounds__(64) void enc2_kernel(
    const uint4* __restrict__ h1, const uint4* __restrict__ e2p,
    const float* __restrict__ e2b, u16* __restrict__ h2) {
  const int wg = blockIdx.x;
  const int rt = wg / 20, nt = wg % 20;
  const int lane = threadIdx.x, q = lane >> 4, c = lane & 15;
  f32x4 acc = {0.f, 0.f, 0.f, 0.f};
  const int arow = rt * 16 + c;
  for (int s = 0; s < 10; ++s) {
    V16 a, b;
    a.u = h1[arow * 40 + s * 4 + q];
    b.u = e2p[(nt * 10 + s) * 64 + lane];      // FIX: e2p has S=10 k-steps per tile
    acc = __builtin_amdgcn_mfma_f32_16x16x32_bf16(a.v, b.v, acc, 0, 0, 0);
  }
  const int col = nt * 16 + c;
  const float bias = (col < 300) ? e2b[col] : 0.f;
#pragma unroll
  for (int i = 0; i < 4; ++i) {
    const int row = rt * 16 + 4 * q + i;
    V16 t; t.h[0] = (col < 300) ? (__bf16)fmaxf(acc[i] + bias, 0.f) : (__bf16)0.f;
    h2[row * 320 + col] = t.s[0];
  }
}

// heads: 64 WGs (rt 16 x t 4) x 64 thr: both zm and zv tiles, then z.
__global__ __launch_bounds__(64) void ench_kernel(
    const uint4* __restrict__ h2, const float* __restrict__ eps,
    const uint4* __restrict__ zmp, const float* __restrict__ zmb,
    const uint4* __restrict__ zvp, const float* __restrict__ zvb,
    float* __restrict__ out) {
  const int wg = blockIdx.x;
  const int rt = wg >> 2, t = wg & 3;
  const int lane = threadIdx.x, q = lane >> 4, c = lane & 15;
  f32x4 am = {0.f, 0.f, 0.f, 0.f}, av = {0.f, 0.f, 0.f, 0.f};
  const int arow = rt * 16 + c;
  for (int s = 0; s < 10; ++s) {
    V16 a, bm, bv;
    a.u = h2[arow * 40 + s * 4 + q];
    bm.u = zmp[(t * 10 + s) * 64 + lane];
    bv.u = zvp[(t * 10 + s) * 64 + lane];
    am = __builtin_amdgcn_mfma_f32_16x16x32_bf16(a.v, bm.v, am, 0, 0, 0);
    av = __builtin_amdgcn_mfma_f32_16x16x32_bf16(a.v, bv.v, av, 0, 0, 0);
  }
  const int col = t * 16 + c;
  const float bm = zmb[col], bv = zvb[col];
#pragma unroll
  for (int i = 0; i < 4; ++i) {
    const int gi = (rt * 16 + 4 * q + i) * 64 + col;
    const float zm = am[i] + bm;
    const float zlv = av[i] + bv;
    out[ZM_OFF + gi] = zm;
    out[ZLV_OFF + gi] = zlv;
    out[Z_OFF + gi] = zm + eps[gi] * expf(0.5f * zlv);
  }
}

// ---------------------------------------------------------------------------
// Fused decoder. 2048 WGs x 320 thr (5 waves). 64 rows/WG (one b).
// Wave u owns n-tiles {4u..4u+3} across all 64 rows -> each b1p/b2p frag read
// exactly once per WG. LDS ~43 KB -> 2 WGs/CU (cross-WG phase overlap).
// Stage 2: g1 = Wb(bf16) @ (diag(z)*gen1^T); g1 -> bf16 LDS [64][328].
// Stage 3: GEMM2 + fused head dot; butterfly + cross-u LDS reduction.
// ---------------------------------------------------------------------------
__global__ __launch_bounds__(320, 3) void dec_kernel(
    const float* __restrict__ z,     // [256][64] (fp32, in d_out)
    const uint4* __restrict__ Wb,    // bf16 [512][64] (8 bf16 per uint4)
    const uint4* __restrict__ b1p,
    const uint4* __restrict__ b2p,
    const float* __restrict__ g2b,
    const float* __restrict__ hw,    // [512][300] fp32
    const float* __restrict__ hb,
    float* __restrict__ xout) {
  __shared__ u16 g1s[64 * 328];     // 41,984 B
  __shared__ float xred[5][64];     // 1,280 B

  const int wg = blockIdx.x;
  const int r0 = wg << 6;           // 64 rows per WG
  const int bi = r0 >> 9;
  const int d0 = r0 & 511;
  const int tid = threadIdx.x;
  const int u = tid >> 6;           // wave: n-tiles 4u..4u+3
  const int lane = tid & 63;
  const int q = lane >> 4;
  const int c = lane & 15;

  const float* zrow = z + bi * 64;

  // ---- stage 2 ----
  bf16x8 bz[4][2];
#pragma unroll
  for (int kf = 0; kf < 2; ++kf) {
    F4 z0, z1;
    z0.v = *(const float4*)(zrow + kf * 32 + q * 8);
    z1.v = *(const float4*)(zrow + kf * 32 + q * 8 + 4);
#pragma unroll
    for (int tt = 0; tt < 4; ++tt) {
      V16 r; r.u = b1p[((4 * u + tt) * 2 + kf) * 64 + lane];
      V16 m;
#pragma unroll
      for (int j = 0; j < 4; ++j) {
        m.h[j]     = (__bf16)(bf2f(r.s[j])     * z0.f[j]);
        m.h[4 + j] = (__bf16)(bf2f(r.s[4 + j]) * z1.f[j]);
      }
      bz[tt][kf] = m.v;
    }
  }
  for (int rt = 0; rt < 4; ++rt) {
    const int rowA = rt * 16 + c;
    V16 af0, af1;
    af0.u = Wb[(d0 + rowA) * 8 + q];          // k = q*8
    af1.u = Wb[(d0 + rowA) * 8 + 4 + q];      // k = 32 + q*8
    f32x4 acc[4];
#pragma unroll
    for (int tt = 0; tt < 4; ++tt) acc[tt] = {0.f, 0.f, 0.f, 0.f};
#pragma unroll
    for (int tt = 0; tt < 4; ++tt) {
      acc[tt] = __builtin_amdgcn_mfma_f32_16x16x32_bf16(af0.v, bz[tt][0], acc[tt], 0, 0, 0);
      acc[tt] = __builtin_amdgcn_mfma_f32_16x16x32_bf16(af1.v, bz[tt][1], acc[tt], 0, 0, 0);
    }
    const int rwb = rt * 16 + 4 * q;
#pragma unroll
    for (int tt = 0; tt < 4; ++tt) {
      const int colb = (4 * u + tt) * 16 + c;
#pragma unroll
      for (int i = 0; i < 4; ++i) {
        V16 t; t.h[0] = (__bf16)fmaxf(acc[tt][i], 0.f);
        g1s[(rwb + i) * 328 + colb] = t.s[0];
      }
    }
  }
  __syncthreads();

  // ---- stage 3 ----
  f32x4 a3[4][4];   // [tt][rt]
#pragma unroll
  for (int tt = 0; tt < 4; ++tt)
#pragma unroll
    for (int rt = 0; rt < 4; ++rt) a3[tt][rt] = {0.f, 0.f, 0.f, 0.f};
  for (int s = 0; s < 10; ++s) {
    V16 b[4];
#pragma unroll
    for (int tt = 0; tt < 4; ++tt) b[tt].u = b2p[((4 * u + tt) * 10 + s) * 64 + lane];
#pragma unroll
    for (int rt = 0; rt < 4; ++rt) {
      V16 a; a.u = *(const uint4*)&g1s[(rt * 16 + c) * 328 + s * 32 + q * 8];
#pragma unroll
      for (int tt = 0; tt < 4; ++tt)
        a3[tt][rt] = __builtin_amdgcn_mfma_f32_16x16x32_bf16(a.v, b[tt].v, a3[tt][rt], 0, 0, 0);
    }
  }
  float xacc[4][4];   // [rt][i]
#pragma unroll
  for (int rt = 0; rt < 4; ++rt)
#pragma unroll
    for (int i = 0; i < 4; ++i) xacc[rt][i] = 0.f;
#pragma unroll
  for (int tt = 0; tt < 4; ++tt) {
    const int col = (4 * u + tt) * 16 + c;
    const bool inb = (col < 300);
    const float bias = inb ? g2b[col] : 0.f;
#pragma unroll
    for (int rt = 0; rt < 4; ++rt)
#pragma unroll
      for (int i = 0; i < 4; ++i) {
        const float g2v = fmaxf(a3[tt][rt][i] + bias, 0.f);
        const float h = inb ? hw[(d0 + rt * 16 + 4 * q + i) * 300 + col] : 0.f;
        xacc[rt][i] += g2v * h;
      }
  }
#pragma unroll
  for (int rt = 0; rt < 4; ++rt)
#pragma unroll
    for (int i = 0; i < 4; ++i) {
      float t = xacc[rt][i];
      t += __shfl_xor(t, 1);
      t += __shfl_xor(t, 2);
      t += __shfl_xor(t, 4);
      t += __shfl_xor(t, 8);
      xacc[rt][i] = t;
    }
  if (c < 4) {
#pragma unroll
    for (int rt = 0; rt < 4; ++rt) {
      float t = xacc[rt][0];
      t = (c == 1) ? xacc[rt][1] : t;
      t = (c == 2) ? xacc[rt][2] : t;
      t = (c == 3) ? xacc[rt][3] : t;
      xred[u][rt * 16 + 4 * q + c] = t;
    }
  }
  __syncthreads();
  if (tid < 64) {
    float t = hb[d0 + tid];
#pragma unroll
    for (int uu = 0; uu < 5; ++uu) t += xred[uu][tid];
    xout[r0 + tid] = t;
  }
}

extern "C" void kernel_launch(void* const* d_in, const int* in_sizes, int n_in,
                              void* d_out, int out_size, void* d_ws, size_t ws_size,
                              hipStream_t stream) {
  const float* x   = (const float*)d_in[0];
  const float* eps = (const float*)d_in[1];
  const float* W   = (const float*)d_in[2];
  const float* e1w = (const float*)d_in[3];
  const float* e1b = (const float*)d_in[4];
  const float* e2w = (const float*)d_in[5];
  const float* e2b = (const float*)d_in[6];
  const float* zmw = (const float*)d_in[7];
  const float* zmb = (const float*)d_in[8];
  const float* zvw = (const float*)d_in[9];
  const float* zvb = (const float*)d_in[10];
  const float* g1w = (const float*)d_in[11];
  const float* g2w = (const float*)d_in[12];
  const float* g2b = (const float*)d_in[13];
  const float* hw  = (const float*)d_in[14];
  const float* hb  = (const float*)d_in[15];
  float* out = (float*)d_out;
  uint4* ws4 = (uint4*)d_ws;

  pack_kernel<<<(PACK_THREADS + 255) / 256, 256, 0, stream>>>(
      g1w, g2w, e1w, e2w, zmw, zvw, W, x, ws4);
  enc1_kernel<<<320, 64, 0, stream>>>(ws4 + XB4, ws4 + E1_OFF, e1b, (u16*)(ws4 + H1_4));
  enc2_kernel<<<320, 64, 0, stream>>>(ws4 + H1_4, ws4 + E2_OFF, e2b, (u16*)(ws4 + H2_4));
  ench_kernel<<<64, 64, 0, stream>>>(ws4 + H2_4, eps,
                                     ws4 + ZMP_OFF, zmb, ws4 + ZVP_OFF, zvb, out);
  dec_kernel<<<2048, 320, 0, stream>>>(out + Z_OFF, ws4 + WB4,
                                       ws4 + B1_OFF, ws4 + B2_OFF,
                                       g2b, hw, hb, out);
}

// Round 7
// 164.323 us; speedup vs baseline: 1.3500x; 1.1197x over previous
//
#include <hip/hip_runtime.h>

typedef unsigned short u16;
typedef unsigned int u32;

typedef __bf16 bf16x8 __attribute__((ext_vector_type(8)));
typedef float f32x4 __attribute__((ext_vector_type(4)));

union V16 { uint4 u; bf16x8 v; u16 s[8]; __bf16 h[8]; };
union F4  { float4 v; float f[4]; };

__device__ __forceinline__ float bf2f(u16 a) {
  union { u32 u; float f; } c; c.u = ((u32)a) << 16; return c.f;
}

#define Z_OFF   131072
#define ZM_OFF  147456
#define ZLV_OFF 163840

// ws layout in uint4 units.
// Fragment packs (b-frag elem j of lane: B[k=s*32+(lane>>4)*8+j][n=t*16+(lane&15)]):
#define B1_OFF 0        // gen1_w: t<20, s<2
#define B2_OFF 2560     // gen2_w: t<20, s<10
#define E1_OFF 15360    // enc1_w: t<20, s<16
#define E2_OFF 35840    // enc2_w: t<20, s<10
#define ZMP_OFF 48640   // zm_w: t<4, s<10
#define ZVP_OFF 51200   // zv_w: t<4, s<10
#define FRAG_TOTAL 53760
// bf16 row-major tables (uint4 = 8 bf16):
#define WB4  53760      // W bf16 [512][64]     : 4096 uint4
#define XB4  57856      // x bf16 [256][512]    : 16384 uint4
#define H1_4 74240      // h1 bf16 [256][320]   : 10240 uint4
#define H2_4 84480      // h2 bf16 [256][320]   : 10240 uint4
#define PACK_THREADS (FRAG_TOTAL + 4096 + 16384)   // 74240

__device__ __forceinline__ void pack_one(const float* __restrict__ src,
                                         int t, int s, int lane,
                                         int Nsrc, int Ksrc, int rowlen,
                                         uint4* __restrict__ dst) {
  const int n = t * 16 + (lane & 15);
  const int k0 = s * 32 + ((lane >> 4) << 3);
  V16 v;
#pragma unroll
  for (int j = 0; j < 8; ++j) {
    const int k = k0 + j;
    v.h[j] = (n < Nsrc && k < Ksrc) ? (__bf16)src[n * rowlen + k] : (__bf16)0.f;
  }
  *dst = v.u;
}

__device__ __forceinline__ void cvt8(const float* __restrict__ src, uint4* __restrict__ dst) {
  F4 a, b; a.v = *(const float4*)src; b.v = *(const float4*)(src + 4);
  V16 v;
#pragma unroll
  for (int j = 0; j < 4; ++j) { v.h[j] = (__bf16)a.f[j]; v.h[4 + j] = (__bf16)b.f[j]; }
  *dst = v.u;
}

__global__ __launch_bounds__(256) void pack_kernel(
    const float* __restrict__ g1w, const float* __restrict__ g2w,
    const float* __restrict__ e1w, const float* __restrict__ e2w,
    const float* __restrict__ zmw, const float* __restrict__ zvw,
    const float* __restrict__ W,   const float* __restrict__ x,
    uint4* __restrict__ ws4) {
  const int idx = blockIdx.x * 256 + threadIdx.x;
  if (idx >= PACK_THREADS) return;
  const int lane = idx & 63;
  if (idx < B2_OFF) {
    const int f = (idx - B1_OFF) >> 6;
    pack_one(g1w, f >> 1, f & 1, lane, 300, 64, 64, ws4 + idx);
  } else if (idx < E1_OFF) {
    const int f = (idx - B2_OFF) >> 6;
    pack_one(g2w, f / 10, f % 10, lane, 300, 300, 300, ws4 + idx);
  } else if (idx < E2_OFF) {
    const int f = (idx - E1_OFF) >> 6;
    pack_one(e1w, f >> 4, f & 15, lane, 300, 512, 512, ws4 + idx);
  } else if (idx < ZMP_OFF) {
    const int f = (idx - E2_OFF) >> 6;
    pack_one(e2w, f / 10, f % 10, lane, 300, 300, 300, ws4 + idx);
  } else if (idx < ZVP_OFF) {
    const int f = (idx - ZMP_OFF) >> 6;
    pack_one(zmw, f / 10, f % 10, lane, 64, 300, 300, ws4 + idx);
  } else if (idx < FRAG_TOTAL) {
    const int f = (idx - ZVP_OFF) >> 6;
    pack_one(zvw, f / 10, f % 10, lane, 64, 300, 300, ws4 + idx);
  } else if (idx < FRAG_TOTAL + 4096) {
    const int i = idx - FRAG_TOTAL;
    cvt8(W + i * 8, ws4 + WB4 + i);
  } else {
    const int i = idx - FRAG_TOTAL - 4096;
    cvt8(x + i * 8, ws4 + XB4 + i);
  }
}

// ---------------------------------------------------------------------------
// enc1: 320 WGs (rt 16 x nt 20) x 64 thr. Fully unrolled K so all 32 loads
// issue before the MFMA chain.
// ---------------------------------------------------------------------------
__global__ __launch_bounds__(64) void enc1_kernel(
    const uint4* __restrict__ xb, const uint4* __restrict__ e1p,
    const float* __restrict__ e1b, u16* __restrict__ h1) {
  const int wg = blockIdx.x;
  const int rt = wg / 20, nt = wg % 20;
  const int lane = threadIdx.x, q = lane >> 4, c = lane & 15;
  f32x4 acc = {0.f, 0.f, 0.f, 0.f};
  const int arow = rt * 16 + c;
#pragma unroll
  for (int s = 0; s < 16; ++s) {
    V16 a, b;
    a.u = xb[arow * 64 + s * 4 + q];
    b.u = e1p[(nt * 16 + s) * 64 + lane];
    acc = __builtin_amdgcn_mfma_f32_16x16x32_bf16(a.v, b.v, acc, 0, 0, 0);
  }
  const int col = nt * 16 + c;
  const float bias = (col < 300) ? e1b[col] : 0.f;
#pragma unroll
  for (int i = 0; i < 4; ++i) {
    const int row = rt * 16 + 4 * q + i;
    V16 t; t.h[0] = (col < 300) ? (__bf16)fmaxf(acc[i] + bias, 0.f) : (__bf16)0.f;
    h1[row * 320 + col] = t.s[0];
  }
}

// enc2: same shape, K=320 (10 steps), A from h1, writes h2.
__global__ __launch_bounds__(64) void enc2_kernel(
    const uint4* __restrict__ h1, const uint4* __restrict__ e2p,
    const float* __restrict__ e2b, u16* __restrict__ h2) {
  const int wg = blockIdx.x;
  const int rt = wg / 20, nt = wg % 20;
  const int lane = threadIdx.x, q = lane >> 4, c = lane & 15;
  f32x4 acc = {0.f, 0.f, 0.f, 0.f};
  const int arow = rt * 16 + c;
#pragma unroll
  for (int s = 0; s < 10; ++s) {
    V16 a, b;
    a.u = h1[arow * 40 + s * 4 + q];
    b.u = e2p[(nt * 10 + s) * 64 + lane];
    acc = __builtin_amdgcn_mfma_f32_16x16x32_bf16(a.v, b.v, acc, 0, 0, 0);
  }
  const int col = nt * 16 + c;
  const float bias = (col < 300) ? e2b[col] : 0.f;
#pragma unroll
  for (int i = 0; i < 4; ++i) {
    const int row = rt * 16 + 4 * q + i;
    V16 t; t.h[0] = (col < 300) ? (__bf16)fmaxf(acc[i] + bias, 0.f) : (__bf16)0.f;
    h2[row * 320 + col] = t.s[0];
  }
}

// heads: 64 WGs (rt 16 x t 4) x 64 thr: both zm and zv tiles, then z.
__global__ __launch_bounds__(64) void ench_kernel(
    const uint4* __restrict__ h2, const float* __restrict__ eps,
    const uint4* __restrict__ zmp, const float* __restrict__ zmb,
    const uint4* __restrict__ zvp, const float* __restrict__ zvb,
    float* __restrict__ out) {
  const int wg = blockIdx.x;
  const int rt = wg >> 2, t = wg & 3;
  const int lane = threadIdx.x, q = lane >> 4, c = lane & 15;
  f32x4 am = {0.f, 0.f, 0.f, 0.f}, av = {0.f, 0.f, 0.f, 0.f};
  const int arow = rt * 16 + c;
#pragma unroll
  for (int s = 0; s < 10; ++s) {
    V16 a, bm, bv;
    a.u = h2[arow * 40 + s * 4 + q];
    bm.u = zmp[(t * 10 + s) * 64 + lane];
    bv.u = zvp[(t * 10 + s) * 64 + lane];
    am = __builtin_amdgcn_mfma_f32_16x16x32_bf16(a.v, bm.v, am, 0, 0, 0);
    av = __builtin_amdgcn_mfma_f32_16x16x32_bf16(a.v, bv.v, av, 0, 0, 0);
  }
  const int col = t * 16 + c;
  const float bm = zmb[col], bv = zvb[col];
#pragma unroll
  for (int i = 0; i < 4; ++i) {
    const int gi = (rt * 16 + 4 * q + i) * 64 + col;
    const float zm = am[i] + bm;
    const float zlv = av[i] + bv;
    out[ZM_OFF + gi] = zm;
    out[ZLV_OFF + gi] = zlv;
    out[Z_OFF + gi] = zm + eps[gi] * expf(0.5f * zlv);
  }
}

// ---------------------------------------------------------------------------
// Fused decoder. 4096 WGs x 320 thr (5 waves). 32 rows/WG (one b).
// LDS = 20,992 B (g1s only; the cross-wave reduce buffer ALIASES g1s after a
// barrier) -> target 2+ WGs/CU under the empirical 64KB-occupancy-pool.
// Wave u owns n-tiles {4u..4u+3}; each b1p/b2p frag read once per WG.
// ---------------------------------------------------------------------------
__global__ __launch_bounds__(320, 4) void dec_kernel(
    const float* __restrict__ z,     // [256][64] (fp32, in d_out)
    const uint4* __restrict__ Wb,    // bf16 [512][64]
    const uint4* __restrict__ b1p,
    const uint4* __restrict__ b2p,
    const float* __restrict__ g2b,
    const float* __restrict__ hw,    // [512][300] fp32
    const float* __restrict__ hb,
    float* __restrict__ xout) {
  __shared__ u16 g1s[32 * 328];     // 20,992 B (also reused as xred after barrier)
  float* xredf = (float*)g1s;       // [5][32] floats = 640 B, aliased

  const int wg = blockIdx.x;
  const int r0 = wg << 5;           // 32 rows per WG
  const int bi = wg >> 4;           // r0 >> 9
  const int d0 = r0 & 511;
  const int tid = threadIdx.x;
  const int u = tid >> 6;           // wave: n-tiles 4u..4u+3
  const int lane = tid & 63;
  const int q = lane >> 4;
  const int c = lane & 15;

  const float* zrow = z + bi * 64;

  // ---- stage 2 ----
  bf16x8 bz[4][2];
#pragma unroll
  for (int kf = 0; kf < 2; ++kf) {
    F4 z0, z1;
    z0.v = *(const float4*)(zrow + kf * 32 + q * 8);
    z1.v = *(const float4*)(zrow + kf * 32 + q * 8 + 4);
#pragma unroll
    for (int tt = 0; tt < 4; ++tt) {
      V16 r; r.u = b1p[((4 * u + tt) * 2 + kf) * 64 + lane];
      V16 m;
#pragma unroll
      for (int j = 0; j < 4; ++j) {
        m.h[j]     = (__bf16)(bf2f(r.s[j])     * z0.f[j]);
        m.h[4 + j] = (__bf16)(bf2f(r.s[4 + j]) * z1.f[j]);
      }
      bz[tt][kf] = m.v;
    }
  }
#pragma unroll
  for (int rt = 0; rt < 2; ++rt) {
    const int rowA = rt * 16 + c;
    V16 af0, af1;
    af0.u = Wb[(d0 + rowA) * 8 + q];          // k = q*8
    af1.u = Wb[(d0 + rowA) * 8 + 4 + q];      // k = 32 + q*8
    f32x4 acc[4];
#pragma unroll
    for (int tt = 0; tt < 4; ++tt) acc[tt] = {0.f, 0.f, 0.f, 0.f};
#pragma unroll
    for (int tt = 0; tt < 4; ++tt) {
      acc[tt] = __builtin_amdgcn_mfma_f32_16x16x32_bf16(af0.v, bz[tt][0], acc[tt], 0, 0, 0);
      acc[tt] = __builtin_amdgcn_mfma_f32_16x16x32_bf16(af1.v, bz[tt][1], acc[tt], 0, 0, 0);
    }
    const int rwb = rt * 16 + 4 * q;
#pragma unroll
    for (int tt = 0; tt < 4; ++tt) {
      const int colb = (4 * u + tt) * 16 + c;
#pragma unroll
      for (int i = 0; i < 4; ++i) {
        V16 t; t.h[0] = (__bf16)fmaxf(acc[tt][i], 0.f);
        g1s[(rwb + i) * 328 + colb] = t.s[0];
      }
    }
  }
  __syncthreads();

  // ---- stage 3 ----
  f32x4 a3[4][2];   // [tt][rt]
#pragma unroll
  for (int tt = 0; tt < 4; ++tt)
#pragma unroll
    for (int rt = 0; rt < 2; ++rt) a3[tt][rt] = {0.f, 0.f, 0.f, 0.f};
  for (int s = 0; s < 10; ++s) {
    V16 b[4];
#pragma unroll
    for (int tt = 0; tt < 4; ++tt) b[tt].u = b2p[((4 * u + tt) * 10 + s) * 64 + lane];
#pragma unroll
    for (int rt = 0; rt < 2; ++rt) {
      V16 a; a.u = *(const uint4*)&g1s[(rt * 16 + c) * 328 + s * 32 + q * 8];
#pragma unroll
      for (int tt = 0; tt < 4; ++tt)
        a3[tt][rt] = __builtin_amdgcn_mfma_f32_16x16x32_bf16(a.v, b[tt].v, a3[tt][rt], 0, 0, 0);
    }
  }
  float xacc[2][4];   // [rt][i]
#pragma unroll
  for (int rt = 0; rt < 2; ++rt)
#pragma unroll
    for (int i = 0; i < 4; ++i) xacc[rt][i] = 0.f;
#pragma unroll
  for (int tt = 0; tt < 4; ++tt) {
    const int col = (4 * u + tt) * 16 + c;
    const bool inb = (col < 300);
    const float bias = inb ? g2b[col] : 0.f;
#pragma unroll
    for (int rt = 0; rt < 2; ++rt)
#pragma unroll
      for (int i = 0; i < 4; ++i) {
        const float g2v = fmaxf(a3[tt][rt][i] + bias, 0.f);
        const float h = inb ? hw[(d0 + rt * 16 + 4 * q + i) * 300 + col] : 0.f;
        xacc[rt][i] += g2v * h;
      }
  }
#pragma unroll
  for (int rt = 0; rt < 2; ++rt)
#pragma unroll
    for (int i = 0; i < 4; ++i) {
      float t = xacc[rt][i];
      t += __shfl_xor(t, 1);
      t += __shfl_xor(t, 2);
      t += __shfl_xor(t, 4);
      t += __shfl_xor(t, 8);
      xacc[rt][i] = t;
    }
  __syncthreads();   // all waves done reading g1s; safe to alias as xred
  if (c < 4) {
#pragma unroll
    for (int rt = 0; rt < 2; ++rt) {
      float t = xacc[rt][0];
      t = (c == 1) ? xacc[rt][1] : t;
      t = (c == 2) ? xacc[rt][2] : t;
      t = (c == 3) ? xacc[rt][3] : t;
      xredf[u * 32 + rt * 16 + 4 * q + c] = t;
    }
  }
  __syncthreads();
  if (tid < 32) {
    float t = hb[d0 + tid];
#pragma unroll
    for (int uu = 0; uu < 5; ++uu) t += xredf[uu * 32 + tid];
    xout[r0 + tid] = t;
  }
}

extern "C" void kernel_launch(void* const* d_in, const int* in_sizes, int n_in,
                              void* d_out, int out_size, void* d_ws, size_t ws_size,
                              hipStream_t stream) {
  const float* x   = (const float*)d_in[0];
  const float* eps = (const float*)d_in[1];
  const float* W   = (const float*)d_in[2];
  const float* e1w = (const float*)d_in[3];
  const float* e1b = (const float*)d_in[4];
  const float* e2w = (const float*)d_in[5];
  const float* e2b = (const float*)d_in[6];
  const float* zmw = (const float*)d_in[7];
  const float* zmb = (const float*)d_in[8];
  const float* zvw = (const float*)d_in[9];
  const float* zvb = (const float*)d_in[10];
  const float* g1w = (const float*)d_in[11];
  const float* g2w = (const float*)d_in[12];
  const float* g2b = (const float*)d_in[13];
  const float* hw  = (const float*)d_in[14];
  const float* hb  = (const float*)d_in[15];
  float* out = (float*)d_out;
  uint4* ws4 = (uint4*)d_ws;

  pack_kernel<<<(PACK_THREADS + 255) / 256, 256, 0, stream>>>(
      g1w, g2w, e1w, e2w, zmw, zvw, W, x, ws4);
  enc1_kernel<<<320, 64, 0, stream>>>(ws4 + XB4, ws4 + E1_OFF, e1b, (u16*)(ws4 + H1_4));
  enc2_kernel<<<320, 64, 0, stream>>>(ws4 + H1_4, ws4 + E2_OFF, e2b, (u16*)(ws4 + H2_4));
  ench_kernel<<<64, 64, 0, stream>>>(ws4 + H2_4, eps,
                                     ws4 + ZMP_OFF, zmb, ws4 + ZVP_OFF, zvb, out);
  dec_kernel<<<4096, 320, 0, stream>>>(out + Z_OFF, ws4 + WB4,
                                       ws4 + B1_OFF, ws4 + B2_OFF,
                                       g2b, hw, hb, out);
}